// Round 1
// baseline (581.441 us; speedup 1.0000x reference)
//
#include <hip/hip_runtime.h>

#define ROI 268
#define NG 512
#define NNODES (NG * ROI)   // 137216
#define CH 32
#define SLOPE 0.33f
#define BN_EPS 1e-5f
#define SR 34               // k_gin LDS row stride (words)
#define SAW 134             // k_gemm1 sA stride: mod32=6 -> stores/reads <=2-way (free)
#define RPS (ROI + 1)       // row_ptr per-graph stride

__device__ __forceinline__ float leakyf(float v) {
    return v > 0.f ? v : SLOPE * v;
}

// ---------------------------------------------------------------------------
// K1: y0[N,32] = x[N,268] @ W1_0[268,32]  (fp32 vector GEMM)
// 128-thread block = 128 rows; per-thread tile 4 rows x 8 cols.
// Chunked-W staging (4KB) + register prefetch of next chunk.
// amdgpu_waves_per_eu(2,2): pin BOTH min and max waves/EU. launch_bounds(128,2)
// only sets the min; the allocator still chased the 64-VGPR/8-wave tier and
// spilled ~142MB scratch (rocprof: VGPR_Count=64, WRITE_SIZE 159MB vs 18MB
// ideal). Kernel needs ~110 VGPR live; max=2 gives it a 256-VGPR budget and
// removes the incentive to shrink below it.
// ---------------------------------------------------------------------------
__device__ __forceinline__ void k1_loadx(const float* __restrict__ x,
                                         size_t rowbase, int k0, int ksize,
                                         int tid, float4* pf) {
    if (ksize == 32) {
#pragma unroll
        for (int i = 0; i < 8; i++) {
            int f = tid + (i << 7);
            int row = f >> 3, kk = (f & 7) << 2;
            pf[i] = *(const float4*)&x[(rowbase + row) * ROI + k0 + kk];
        }
    } else {   // ksize == 12
#pragma unroll
        for (int i = 0; i < 3; i++)
            pf[i] = *(const float4*)&x[(rowbase + tid) * ROI + k0 + (i << 2)];
    }
}

__device__ __forceinline__ void k1_storex(float* __restrict__ sA, int ksize,
                                          int tid, const float4* pf) {
    if (ksize == 32) {
#pragma unroll
        for (int i = 0; i < 8; i++) {
            int f = tid + (i << 7);
            int row = f >> 3, kk = (f & 7) << 2;
            sA[(kk + 0) * SAW + row] = pf[i].x;
            sA[(kk + 1) * SAW + row] = pf[i].y;
            sA[(kk + 2) * SAW + row] = pf[i].z;
            sA[(kk + 3) * SAW + row] = pf[i].w;
        }
    } else {
#pragma unroll
        for (int i = 0; i < 3; i++) {
            int kk = i << 2;
            sA[(kk + 0) * SAW + tid] = pf[i].x;
            sA[(kk + 1) * SAW + tid] = pf[i].y;
            sA[(kk + 2) * SAW + tid] = pf[i].z;
            sA[(kk + 3) * SAW + tid] = pf[i].w;
        }
    }
}

__global__ __launch_bounds__(128)
__attribute__((amdgpu_waves_per_eu(2, 2))) void k_gemm1(
    const float* __restrict__ x, const float* __restrict__ W1,
    float* __restrict__ y0) {
    __shared__ float sW[32 * CH];     // current k-chunk of W1 (4KB)
    __shared__ float sA[32 * SAW];    // k-major x tile (17.2KB)

    const int tid = threadIdx.x;
    const size_t rowbase = (size_t)blockIdx.x * 128;
    const int rg = tid >> 2;   // 0..31 -> 4 rows each
    const int cg = tid & 3;    // 0..3  -> 8 cols each

    float acc[4][8];
#pragma unroll
    for (int r = 0; r < 4; r++)
#pragma unroll
        for (int c = 0; c < 8; c++) acc[r][c] = 0.f;

    float4 pf[8];
    float4 pw, pw2;

    // prefetch chunk 0
    k1_loadx(x, rowbase, 0, 32, tid, pf);
    pw = ((const float4*)W1)[tid];
    pw2 = ((const float4*)W1)[tid + 128];

    int k0 = 0;
    for (int chunk = 0; chunk < 9; ++chunk) {
        const int ksize = (chunk < 8) ? 32 : 12;
        // store prefetched chunk to LDS
        k1_storex(sA, ksize, tid, pf);
        {
            int nw4 = (ksize * CH) >> 2;   // 256 or 96
            if (tid < nw4) ((float4*)sW)[tid] = pw;
            if (tid + 128 < nw4) ((float4*)sW)[tid + 128] = pw2;
        }
        __syncthreads();
        // issue next chunk's global loads (in flight during compute)
        if (chunk + 1 < 9) {
            int nk0 = k0 + ksize;
            int nks = (chunk + 1 < 8) ? 32 : 12;
            k1_loadx(x, rowbase, nk0, nks, tid, pf);
            int nw4 = (nks * CH) >> 2;
            if (tid < nw4) pw = ((const float4*)(W1 + nk0 * CH))[tid];
            if (tid + 128 < nw4) pw2 = ((const float4*)(W1 + nk0 * CH))[tid + 128];
        }
#pragma unroll 4
        for (int kk = 0; kk < ksize; ++kk) {
            float4 a4 = *(float4*)&sA[kk * SAW + rg * 4];
            const float* wr = &sW[kk * CH + cg * 8];
            float4 w0 = *(const float4*)wr;
            float4 w1 = *(const float4*)(wr + 4);
            float av[4] = {a4.x, a4.y, a4.z, a4.w};
            float wv[8] = {w0.x, w0.y, w0.z, w0.w, w1.x, w1.y, w1.z, w1.w};
#pragma unroll
            for (int r = 0; r < 4; r++)
#pragma unroll
                for (int c = 0; c < 8; c++) acc[r][c] += av[r] * wv[c];
        }
        k0 += ksize;
        __syncthreads();
    }

#pragma unroll
    for (int r = 0; r < 4; r++) {
        size_t row = rowbase + rg * 4 + r;
        *(float4*)&y0[row * CH + cg * 8] =
            make_float4(acc[r][0], acc[r][1], acc[r][2], acc[r][3]);
        *(float4*)&y0[row * CH + cg * 8 + 4] =
            make_float4(acc[r][4], acc[r][5], acc[r][6], acc[r][7]);
    }
}

// ---------------------------------------------------------------------------
// K2: CSR build (by dst node): deg -> per-graph scan + atomic base ticket ->
// fill. row_ptr layout [NG][ROI+1] so per-graph bases are order-free.
// ---------------------------------------------------------------------------
__global__ void k_deg(const int* __restrict__ dst, int E, int* __restrict__ deg) {
    int stride = gridDim.x * blockDim.x;
    for (int i = blockIdx.x * blockDim.x + threadIdx.x; i < E; i += stride)
        atomicAdd(&deg[dst[i]], 1);
}

__global__ __launch_bounds__(512) void k_scan_local(
    int* __restrict__ deg, int* __restrict__ ticket, int* __restrict__ row_ptr) {
    __shared__ int s[512];
    __shared__ int sbase;
    const int g = blockIdx.x, t = threadIdx.x;
    int v = (t < ROI) ? deg[g * ROI + t] : 0;
    s[t] = v;
    __syncthreads();
    for (int d = 1; d < 512; d <<= 1) {
        int u = (t >= d) ? s[t - d] : 0;
        __syncthreads();
        s[t] += u;
        __syncthreads();
    }
    if (t == 511) sbase = atomicAdd(ticket, s[511]);
    __syncthreads();
    const int base = sbase;
    if (t < ROI) {
        int exc = base + s[t] - v;
        row_ptr[g * RPS + t] = exc;
        deg[g * ROI + t] = exc;   // becomes fill cursor
    }
    if (t == 511) row_ptr[g * RPS + ROI] = base + s[511];
}

__global__ void k_fill(const int* __restrict__ src, const int* __restrict__ dst,
                       int E, int* __restrict__ rcur, int* __restrict__ ebuf) {
    int stride = gridDim.x * blockDim.x;
    for (int i = blockIdx.x * blockDim.x + threadIdx.x; i < E; i += stride) {
        int d = dst[i];
        int g = d / ROI;
        int pos = atomicAdd(&rcur[d], 1);
        ebuf[pos] = (src[i] - g * ROI) * SR;   // premultiplied LDS word offset
    }
}

// ---------------------------------------------------------------------------
// K3 helpers
// ---------------------------------------------------------------------------
__device__ __forceinline__ void gather_combine(
    const float* __restrict__ in, float* __restrict__ out,
    const int* __restrict__ rp, const int* __restrict__ ebuf, float e,
    const float* __restrict__ b1, int t) {
    const int ch = t & 31;
    const int hw = t >> 5;   // 0..15
    for (int n = hw; n < ROI; n += 16) {
        int b = rp[n], en = rp[n + 1];
        float acc = 0.f;
        int j = b;
        for (; j + 3 < en; j += 4) {
            int p0 = ebuf[j], p1 = ebuf[j + 1], p2 = ebuf[j + 2], p3 = ebuf[j + 3];
            float v0 = in[p0 + ch], v1 = in[p1 + ch];
            float v2 = in[p2 + ch], v3 = in[p3 + ch];
            acc += (v0 + v1) + (v2 + v3);
        }
        for (; j < en; ++j) acc += in[ebuf[j] + ch];
        out[n * SR + ch] = leakyf(e * in[n * SR + ch] + acc + b1[ch]);
    }
}

template <bool AFFINE>
__device__ __forceinline__ void gemm_inplace(float* __restrict__ buf,
                                             const float* __restrict__ w,
                                             const float* __restrict__ bias,
                                             const float* __restrict__ sc,
                                             const float* __restrict__ sh, int t) {
    for (int u = t; u < ROI * 2; u += 512) {
        const int r0 = (u >> 2) * 2;
        const int cq = u & 3;
        float acc0[8], acc1[8];
#pragma unroll
        for (int c = 0; c < 8; c++) {
            float b = AFFINE ? bias[cq * 8 + c] : 0.f;
            acc0[c] = b;
            acc1[c] = b;
        }
        const float* row0 = &buf[r0 * SR];
        const float* row1 = row0 + SR;
        // unroll 2 ONLY: full unroll software-pipelines all 64 w-float4s
        // -> >128 VGPR -> scratch spill -> 1 GB HBM (rounds 2/3)
#pragma unroll 2
        for (int k = 0; k < CH; k += 2) {
            float2 a0 = *(const float2*)&row0[k];
            float2 a1 = *(const float2*)&row1[k];
            const float* wr0 = &w[k * CH + cq * 8];
            const float* wr1 = wr0 + CH;
            float4 wa = *(const float4*)wr0;
            float4 wb = *(const float4*)(wr0 + 4);
            float4 wc = *(const float4*)wr1;
            float4 wd = *(const float4*)(wr1 + 4);
            acc0[0] += a0.x * wa.x + a0.y * wc.x;
            acc0[1] += a0.x * wa.y + a0.y * wc.y;
            acc0[2] += a0.x * wa.z + a0.y * wc.z;
            acc0[3] += a0.x * wa.w + a0.y * wc.w;
            acc0[4] += a0.x * wb.x + a0.y * wd.x;
            acc0[5] += a0.x * wb.y + a0.y * wd.y;
            acc0[6] += a0.x * wb.z + a0.y * wd.z;
            acc0[7] += a0.x * wb.w + a0.y * wd.w;
            acc1[0] += a1.x * wa.x + a1.y * wc.x;
            acc1[1] += a1.x * wa.y + a1.y * wc.y;
            acc1[2] += a1.x * wa.z + a1.y * wc.z;
            acc1[3] += a1.x * wa.w + a1.y * wc.w;
            acc1[4] += a1.x * wb.x + a1.y * wd.x;
            acc1[5] += a1.x * wb.y + a1.y * wd.y;
            acc1[6] += a1.x * wb.z + a1.y * wd.z;
            acc1[7] += a1.x * wb.w + a1.y * wd.w;
        }
        float* o0 = &buf[r0 * SR + cq * 8];
        float* o1 = o0 + SR;
#pragma unroll
        for (int c = 0; c < 8; c += 2) {
            float h00 = acc0[c], h01 = acc0[c + 1];
            float h10 = acc1[c], h11 = acc1[c + 1];
            if (AFFINE) {
                float s0 = sc[cq * 8 + c], t0 = sh[cq * 8 + c];
                float s1 = sc[cq * 8 + c + 1], t1 = sh[cq * 8 + c + 1];
                h00 = leakyf(h00 * s0 + t0);
                h01 = leakyf(h01 * s1 + t1);
                h10 = leakyf(h10 * s0 + t0);
                h11 = leakyf(h11 * s1 + t1);
            }
            *(float2*)&o0[c] = make_float2(h00, h01);
            *(float2*)&o1[c] = make_float2(h10, h11);
        }
    }
}

__device__ __forceinline__ void pool_store(const float* __restrict__ h,
                                           float* __restrict__ psc, int t) {
    const int ch = t & 31;
    const int hw = t >> 5;
    const int wave = t >> 6;
    float s = 0.f, m = -1e30f;
    for (int n = hw; n < ROI; n += 16) {
        float v = h[n * SR + ch];
        s += v;
        m = fmaxf(m, v);
    }
    s += __shfl_down(s, 32);
    m = fmaxf(m, __shfl_down(m, 32));
    if ((t & 63) < 32) {
        psc[wave * 32 + ch] = s;
        psc[256 + wave * 32 + ch] = m;
    }
}

__device__ __forceinline__ void pool_final(const float* __restrict__ psc,
                                           float* __restrict__ zg, int t) {
    if (t < 32) {
        float s = 0.f, m = -1e30f;
#pragma unroll
        for (int wv = 0; wv < 8; wv++) {
            s += psc[wv * 32 + t];
            m = fmaxf(m, psc[256 + wv * 32 + t]);
        }
        zg[t] = m;
        zg[CH + t] = s / (float)ROI;
    }
}

// ---------------------------------------------------------------------------
// K3: fused both GIN layers + both poolings. One 512-thr block per graph.
// ---------------------------------------------------------------------------
__global__ __launch_bounds__(512, 2) void k_gin(
    const float* __restrict__ y0, const int* __restrict__ row_ptr,
    const int* __restrict__ ebuf, const float* __restrict__ eps0p,
    const float* __restrict__ b1_0, const float* __restrict__ W2_0,
    const float* __restrict__ b2_0, const float* __restrict__ bn0_g,
    const float* __restrict__ bn0_b, const float* __restrict__ bn0_m,
    const float* __restrict__ bn0_v, const float* __restrict__ eps1p,
    const float* __restrict__ W1_1, const float* __restrict__ b1_1,
    const float* __restrict__ W2_1, const float* __restrict__ b2_1,
    const float* __restrict__ bn1_g, const float* __restrict__ bn1_b,
    const float* __restrict__ bn1_m, const float* __restrict__ bn1_v,
    float* __restrict__ z) {
    __shared__ float bufA[ROI * SR];
    __shared__ float bufB[ROI * SR];
    __shared__ float w[CH * CH];
    __shared__ float prm[8 * CH];
    __shared__ float psc[512];
    __shared__ float epss[2];

    const int t = threadIdx.x;
    const int g = blockIdx.x;

    if (t < CH) {
        prm[0 * CH + t] = b1_0[t];
        prm[1 * CH + t] = b2_0[t];
        float s0 = bn0_g[t] * rsqrtf(bn0_v[t] + BN_EPS);
        prm[2 * CH + t] = s0;
        prm[3 * CH + t] = bn0_b[t] - bn0_m[t] * s0;
        prm[4 * CH + t] = b1_1[t];
        prm[5 * CH + t] = b2_1[t];
        float s1 = bn1_g[t] * rsqrtf(bn1_v[t] + BN_EPS);
        prm[6 * CH + t] = s1;
        prm[7 * CH + t] = bn1_b[t] - bn1_m[t] * s1;
    }
    if (t == 0) {
        epss[0] = 1.0f + *eps0p;
        epss[1] = 1.0f + *eps1p;
    }

    const float* yg = y0 + (size_t)g * ROI * CH;
    for (int f = t; f < (ROI * CH) / 4; f += 512) {
        float4 v = ((const float4*)yg)[f];
        int row = f >> 3, c4 = (f & 7) << 2;
        float* p = &bufA[row * SR + c4];
        *(float2*)p = make_float2(v.x, v.y);
        *(float2*)(p + 2) = make_float2(v.z, v.w);
    }
    for (int i = t; i < (CH * CH) / 4; i += 512)
        ((float4*)w)[i] = ((const float4*)W2_0)[i];
    __syncthreads();

    const int* rp = row_ptr + g * RPS;

    gather_combine(bufA, bufB, rp, ebuf, epss[0], &prm[0 * CH], t);
    __syncthreads();

    gemm_inplace<true>(bufB, w, &prm[1 * CH], &prm[2 * CH], &prm[3 * CH], t);
    __syncthreads();

    pool_store(bufB, psc, t);
    for (int i = t; i < (CH * CH) / 4; i += 512)
        ((float4*)w)[i] = ((const float4*)W1_1)[i];
    __syncthreads();

    pool_final(psc, z + (size_t)g * 128, t);
    gemm_inplace<false>(bufB, w, nullptr, nullptr, nullptr, t);
    __syncthreads();

    gather_combine(bufB, bufA, rp, ebuf, epss[1], &prm[4 * CH], t);
    for (int i = t; i < (CH * CH) / 4; i += 512)
        ((float4*)w)[i] = ((const float4*)W2_1)[i];
    __syncthreads();

    gemm_inplace<true>(bufA, w, &prm[5 * CH], &prm[6 * CH], &prm[7 * CH], t);
    __syncthreads();

    pool_store(bufA, psc, t);
    __syncthreads();
    pool_final(psc, z + (size_t)g * 128 + 64, t);
}

// ---------------------------------------------------------------------------
// K4: head MLP  z[512,128] -> 256 -> 128 -> 1
// ---------------------------------------------------------------------------
__global__ __launch_bounds__(256) void k_head(
    const float* __restrict__ z, const float* __restrict__ W1,
    const float* __restrict__ b1, const float* __restrict__ g1,
    const float* __restrict__ be1, const float* __restrict__ m1,
    const float* __restrict__ v1, const float* __restrict__ W2,
    const float* __restrict__ b2, const float* __restrict__ g2,
    const float* __restrict__ be2, const float* __restrict__ m2,
    const float* __restrict__ v2, const float* __restrict__ W3,
    const float* __restrict__ b3, float* __restrict__ out) {
    __shared__ float zr[128], z1[256], z2[128];
    const int t = threadIdx.x;
    const int g = blockIdx.x;

    if (t < 32) ((float4*)zr)[t] = ((const float4*)(z + (size_t)g * 128))[t];
    __syncthreads();
    {
        float acc = b1[t];
#pragma unroll 8
        for (int k = 0; k < 128; k++) acc += zr[k] * W1[k * 256 + t];
        float s = g1[t] * rsqrtf(v1[t] + BN_EPS);
        acc = (acc - m1[t]) * s + be1[t];
        z1[t] = leakyf(acc);
    }
    __syncthreads();
    if (t < 128) {
        float acc = b2[t];
#pragma unroll 8
        for (int k = 0; k < 256; k++) acc += z1[k] * W2[k * 128 + t];
        float s = g2[t] * rsqrtf(v2[t] + BN_EPS);
        acc = (acc - m2[t]) * s + be2[t];
        z2[t] = leakyf(acc);
    }
    __syncthreads();
    if (t < 64) {
        float v = z2[t] * W3[t] + z2[t + 64] * W3[t + 64];
        for (int offd = 32; offd; offd >>= 1) v += __shfl_down(v, offd);
        if (t == 0) out[g] = v + b3[0];
    }
}

// ---------------------------------------------------------------------------
extern "C" void kernel_launch(void* const* d_in, const int* in_sizes, int n_in,
                              void* d_out, int out_size, void* d_ws, size_t ws_size,
                              hipStream_t stream) {
    const float* x      = (const float*)d_in[0];
    const int* eidx     = (const int*)d_in[1];
    const float* eps0   = (const float*)d_in[3];
    const float* W1_0   = (const float*)d_in[4];
    const float* b1_0   = (const float*)d_in[5];
    const float* W2_0   = (const float*)d_in[6];
    const float* b2_0   = (const float*)d_in[7];
    const float* bn0_g  = (const float*)d_in[8];
    const float* bn0_b  = (const float*)d_in[9];
    const float* bn0_m  = (const float*)d_in[10];
    const float* bn0_v  = (const float*)d_in[11];
    const float* eps1   = (const float*)d_in[12];
    const float* W1_1   = (const float*)d_in[13];
    const float* b1_1   = (const float*)d_in[14];
    const float* W2_1   = (const float*)d_in[15];
    const float* b2_1   = (const float*)d_in[16];
    const float* bn1_g  = (const float*)d_in[17];
    const float* bn1_b  = (const float*)d_in[18];
    const float* bn1_m  = (const float*)d_in[19];
    const float* bn1_v  = (const float*)d_in[20];
    const float* lin1_W = (const float*)d_in[21];
    const float* lin1_b = (const float*)d_in[22];
    const float* hbn1_g = (const float*)d_in[23];
    const float* hbn1_b = (const float*)d_in[24];
    const float* hbn1_m = (const float*)d_in[25];
    const float* hbn1_v = (const float*)d_in[26];
    const float* lin2_W = (const float*)d_in[27];
    const float* lin2_b = (const float*)d_in[28];
    const float* hbn2_g = (const float*)d_in[29];
    const float* hbn2_b = (const float*)d_in[30];
    const float* hbn2_m = (const float*)d_in[31];
    const float* hbn2_v = (const float*)d_in[32];
    const float* lin3_W = (const float*)d_in[33];
    const float* lin3_b = (const float*)d_in[34];

    const int E = in_sizes[1] / 2;
    const int* src = eidx;
    const int* dst = eidx + E;

    char* ws = (char*)d_ws;
    const size_t Y0_OFF  = 0;
    const size_t Z_OFF   = (size_t)NNODES * CH * 4;          // 17,563,648
    const size_t DEG_OFF = Z_OFF + (size_t)NG * 128 * 4;
    const size_t TKT_OFF = DEG_OFF + (size_t)NNODES * 4;     // ticket right after deg
    const size_t RP_OFF  = TKT_OFF + 64;
    const size_t EB_OFF  = RP_OFF + (size_t)(NG * RPS + 4) * 4;

    float* y0    = (float*)(ws + Y0_OFF);
    float* z     = (float*)(ws + Z_OFF);
    int* deg     = (int*)(ws + DEG_OFF);   // degree -> cursor
    int* ticket  = (int*)(ws + TKT_OFF);
    int* row_ptr = (int*)(ws + RP_OFF);
    int* ebuf    = (int*)(ws + EB_OFF);

    k_gemm1<<<NNODES / 128, 128, 0, stream>>>(x, W1_0, y0);

    hipMemsetAsync(deg, 0, (size_t)NNODES * sizeof(int) + 64, stream);
    k_deg<<<1024, 256, 0, stream>>>(dst, E, deg);
    k_scan_local<<<NG, 512, 0, stream>>>(deg, ticket, row_ptr);
    k_fill<<<1024, 256, 0, stream>>>(src, dst, E, deg, ebuf);

    k_gin<<<NG, 512, 0, stream>>>(y0, row_ptr, ebuf, eps0, b1_0, W2_0, b2_0,
                                  bn0_g, bn0_b, bn0_m, bn0_v, eps1, W1_1, b1_1,
                                  W2_1, b2_1, bn1_g, bn1_b, bn1_m, bn1_v, z);

    k_head<<<NG, 256, 0, stream>>>(z, lin1_W, lin1_b, hbn1_g, hbn1_b, hbn1_m,
                                   hbn1_v, lin2_W, lin2_b, hbn2_g, hbn2_b,
                                   hbn2_m, hbn2_v, lin3_W, lin3_b,
                                   (float*)d_out);
}

// Round 2
// 507.588 us; speedup vs baseline: 1.1455x; 1.1455x over previous
//
#include <hip/hip_runtime.h>

#define ROI 268
#define NG 512
#define NNODES (NG * ROI)   // 137216
#define CH 32
#define SLOPE 0.33f
#define BN_EPS 1e-5f
#define SR 34               // k_gin LDS row stride (words)
#define SAS 258             // k_gemm1 sA k-slab stride (words): even -> b64-aligned reads;
                            // mod32=2 -> staging stores exactly 2-way (free, m136)
#define RPS (ROI + 1)       // row_ptr per-graph stride

__device__ __forceinline__ float leakyf(float v) {
    return v > 0.f ? v : SLOPE * v;
}

// ---------------------------------------------------------------------------
// K1: y0[N,32] = x[N,268] @ W1_0[268,32]  (fp32 vector GEMM)
// v2 structure (round 2): 256 threads = 4 waves, 256 rows/block.
//  - Wave w owns cols 8w..8w+7: W read address is wave-uniform (readfirstlane
//    -> SGPR) => same-address broadcast, free. No per-lane W addressing.
//  - Lane l owns rows {2l,2l+1,128+2l,129+2l}: sA reads are contiguous
//    stride-1 b64 (canonical conflict-free). No inter-lane broadcast.
//  - sA stride 258: staging stores (8*(l&7)+(l>>3))%32 = exactly 2-way.
//  - W staged once (34.3KB), not per-chunk. LDS total 65.7KB -> 2 blocks/CU.
//  - waves_per_eu(2,4): 128-VGPR budget for ~100-VGPR kernel; no spill and
//    no LDS padding (round-1 lesson: max=2 padded LDS 21.5->37.9KB).
// ---------------------------------------------------------------------------
__global__ __launch_bounds__(256)
__attribute__((amdgpu_waves_per_eu(2, 4))) void k_gemm1(
    const float* __restrict__ x, const float* __restrict__ W1,
    float* __restrict__ y0) {
    __shared__ float sW[ROI * CH];       // full W1: 34.3KB
    __shared__ float sA[32 * SAS];       // k-major x chunk: 33.0KB

    const int tid = threadIdx.x;
    const int l = tid & 63;
    const int wcb = __builtin_amdgcn_readfirstlane((tid >> 6) << 3);
    const size_t rowbase = (size_t)blockIdx.x * 256;

    float acc[4][8];
#pragma unroll
    for (int r = 0; r < 4; r++)
#pragma unroll
        for (int c = 0; c < 8; c++) acc[r][c] = 0.f;

    // stage all of W1 (linear, once): 2144 float4
#pragma unroll
    for (int i = 0; i < 9; i++) {
        int f = (i << 8) + tid;
        if (f < (ROI * CH) / 4) ((float4*)sW)[f] = ((const float4*)W1)[f];
    }

    // prefetch x chunk 0: f = i*256+tid; row=f>>3 (8 rows/wave-instr, 128B
    // per row -> coalesced); kc=(f&7)*4
    float4 pf[8];
#pragma unroll
    for (int i = 0; i < 8; i++) {
        int f = (i << 8) + tid;
        int row = f >> 3, kc = (f & 7) << 2;
        pf[i] = *(const float4*)&x[(rowbase + row) * ROI + kc];
    }

    int k0 = 0;
    for (int chunk = 0; chunk < 9; ++chunk) {
        const int ksize = (chunk < 8) ? 32 : 12;
        // store prefetched chunk to LDS (k-major transpose)
        if (ksize == 32) {
#pragma unroll
            for (int i = 0; i < 8; i++) {
                int f = (i << 8) + tid;
                int row = f >> 3, kc = (f & 7) << 2;
                sA[(kc + 0) * SAS + row] = pf[i].x;
                sA[(kc + 1) * SAS + row] = pf[i].y;
                sA[(kc + 2) * SAS + row] = pf[i].z;
                sA[(kc + 3) * SAS + row] = pf[i].w;
            }
        } else {
#pragma unroll
            for (int i = 0; i < 3; i++) {
                int kc = i << 2;
                sA[(kc + 0) * SAS + tid] = pf[i].x;
                sA[(kc + 1) * SAS + tid] = pf[i].y;
                sA[(kc + 2) * SAS + tid] = pf[i].z;
                sA[(kc + 3) * SAS + tid] = pf[i].w;
            }
        }
        __syncthreads();
        // issue next chunk's global loads (in flight during compute)
        if (chunk + 1 < 9) {
            const int nk0 = k0 + ksize;
            if (chunk + 1 < 8) {
#pragma unroll
                for (int i = 0; i < 8; i++) {
                    int f = (i << 8) + tid;
                    int row = f >> 3, kc = (f & 7) << 2;
                    pf[i] = *(const float4*)&x[(rowbase + row) * ROI + nk0 + kc];
                }
            } else {
#pragma unroll
                for (int i = 0; i < 3; i++)
                    pf[i] = *(const float4*)&x[(rowbase + tid) * ROI + nk0 + (i << 2)];
            }
        }
        const float* wp = &sW[k0 * CH + wcb];
#pragma unroll 2
        for (int kk = 0; kk < ksize; ++kk) {
            float2 a0 = *(const float2*)&sA[kk * SAS + 2 * l];
            float2 a1 = *(const float2*)&sA[kk * SAS + 128 + 2 * l];
            float4 w0 = *(const float4*)&wp[kk * CH];
            float4 w1 = *(const float4*)&wp[kk * CH + 4];
            float av[4] = {a0.x, a0.y, a1.x, a1.y};
            float wv[8] = {w0.x, w0.y, w0.z, w0.w, w1.x, w1.y, w1.z, w1.w};
#pragma unroll
            for (int r = 0; r < 4; r++)
#pragma unroll
                for (int c = 0; c < 8; c++) acc[r][c] += av[r] * wv[c];
        }
        k0 += ksize;
        __syncthreads();
    }

    // write out: lane rows {2l,2l+1,128+2l,129+2l}, cols wcb..wcb+7
#pragma unroll
    for (int r = 0; r < 4; r++) {
        size_t row = rowbase + ((r < 2) ? (2 * l + r) : (126 + 2 * l + r));
        *(float4*)&y0[row * CH + wcb] =
            make_float4(acc[r][0], acc[r][1], acc[r][2], acc[r][3]);
        *(float4*)&y0[row * CH + wcb + 4] =
            make_float4(acc[r][4], acc[r][5], acc[r][6], acc[r][7]);
    }
}

// ---------------------------------------------------------------------------
// K2: CSR build (by dst node): deg -> per-graph scan + atomic base ticket ->
// fill. row_ptr layout [NG][ROI+1] so per-graph bases are order-free.
// ---------------------------------------------------------------------------
__global__ void k_deg(const int* __restrict__ dst, int E, int* __restrict__ deg) {
    int stride = gridDim.x * blockDim.x;
    for (int i = blockIdx.x * blockDim.x + threadIdx.x; i < E; i += stride)
        atomicAdd(&deg[dst[i]], 1);
}

__global__ __launch_bounds__(512) void k_scan_local(
    int* __restrict__ deg, int* __restrict__ ticket, int* __restrict__ row_ptr) {
    __shared__ int s[512];
    __shared__ int sbase;
    const int g = blockIdx.x, t = threadIdx.x;
    int v = (t < ROI) ? deg[g * ROI + t] : 0;
    s[t] = v;
    __syncthreads();
    for (int d = 1; d < 512; d <<= 1) {
        int u = (t >= d) ? s[t - d] : 0;
        __syncthreads();
        s[t] += u;
        __syncthreads();
    }
    if (t == 511) sbase = atomicAdd(ticket, s[511]);
    __syncthreads();
    const int base = sbase;
    if (t < ROI) {
        int exc = base + s[t] - v;
        row_ptr[g * RPS + t] = exc;
        deg[g * ROI + t] = exc;   // becomes fill cursor
    }
    if (t == 511) row_ptr[g * RPS + ROI] = base + s[511];
}

__global__ void k_fill(const int* __restrict__ src, const int* __restrict__ dst,
                       int E, int* __restrict__ rcur, int* __restrict__ ebuf) {
    int stride = gridDim.x * blockDim.x;
    for (int i = blockIdx.x * blockDim.x + threadIdx.x; i < E; i += stride) {
        int d = dst[i];
        int g = d / ROI;
        int pos = atomicAdd(&rcur[d], 1);
        ebuf[pos] = (src[i] - g * ROI) * SR;   // premultiplied LDS word offset
    }
}

// ---------------------------------------------------------------------------
// K3 helpers
// ---------------------------------------------------------------------------
__device__ __forceinline__ void gather_combine(
    const float* __restrict__ in, float* __restrict__ out,
    const int* __restrict__ rp, const int* __restrict__ ebuf, float e,
    const float* __restrict__ b1, int t) {
    const int ch = t & 31;
    const int hw = t >> 5;   // 0..15
    for (int n = hw; n < ROI; n += 16) {
        int b = rp[n], en = rp[n + 1];
        float acc = 0.f;
        int j = b;
        for (; j + 3 < en; j += 4) {
            int p0 = ebuf[j], p1 = ebuf[j + 1], p2 = ebuf[j + 2], p3 = ebuf[j + 3];
            float v0 = in[p0 + ch], v1 = in[p1 + ch];
            float v2 = in[p2 + ch], v3 = in[p3 + ch];
            acc += (v0 + v1) + (v2 + v3);
        }
        for (; j < en; ++j) acc += in[ebuf[j] + ch];
        out[n * SR + ch] = leakyf(e * in[n * SR + ch] + acc + b1[ch]);
    }
}

template <bool AFFINE>
__device__ __forceinline__ void gemm_inplace(float* __restrict__ buf,
                                             const float* __restrict__ w,
                                             const float* __restrict__ bias,
                                             const float* __restrict__ sc,
                                             const float* __restrict__ sh, int t) {
    for (int u = t; u < ROI * 2; u += 512) {
        const int r0 = (u >> 2) * 2;
        const int cq = u & 3;
        float acc0[8], acc1[8];
#pragma unroll
        for (int c = 0; c < 8; c++) {
            float b = AFFINE ? bias[cq * 8 + c] : 0.f;
            acc0[c] = b;
            acc1[c] = b;
        }
        const float* row0 = &buf[r0 * SR];
        const float* row1 = row0 + SR;
        // unroll 2 ONLY: full unroll software-pipelines all 64 w-float4s
        // -> >128 VGPR -> scratch spill -> 1 GB HBM (rounds 2/3)
#pragma unroll 2
        for (int k = 0; k < CH; k += 2) {
            float2 a0 = *(const float2*)&row0[k];
            float2 a1 = *(const float2*)&row1[k];
            const float* wr0 = &w[k * CH + cq * 8];
            const float* wr1 = wr0 + CH;
            float4 wa = *(const float4*)wr0;
            float4 wb = *(const float4*)(wr0 + 4);
            float4 wc = *(const float4*)wr1;
            float4 wd = *(const float4*)(wr1 + 4);
            acc0[0] += a0.x * wa.x + a0.y * wc.x;
            acc0[1] += a0.x * wa.y + a0.y * wc.y;
            acc0[2] += a0.x * wa.z + a0.y * wc.z;
            acc0[3] += a0.x * wa.w + a0.y * wc.w;
            acc0[4] += a0.x * wb.x + a0.y * wd.x;
            acc0[5] += a0.x * wb.y + a0.y * wd.y;
            acc0[6] += a0.x * wb.z + a0.y * wd.z;
            acc0[7] += a0.x * wb.w + a0.y * wd.w;
            acc1[0] += a1.x * wa.x + a1.y * wc.x;
            acc1[1] += a1.x * wa.y + a1.y * wc.y;
            acc1[2] += a1.x * wa.z + a1.y * wc.z;
            acc1[3] += a1.x * wa.w + a1.y * wc.w;
            acc1[4] += a1.x * wb.x + a1.y * wd.x;
            acc1[5] += a1.x * wb.y + a1.y * wd.y;
            acc1[6] += a1.x * wb.z + a1.y * wd.z;
            acc1[7] += a1.x * wb.w + a1.y * wd.w;
        }
        float* o0 = &buf[r0 * SR + cq * 8];
        float* o1 = o0 + SR;
#pragma unroll
        for (int c = 0; c < 8; c += 2) {
            float h00 = acc0[c], h01 = acc0[c + 1];
            float h10 = acc1[c], h11 = acc1[c + 1];
            if (AFFINE) {
                float s0 = sc[cq * 8 + c], t0 = sh[cq * 8 + c];
                float s1 = sc[cq * 8 + c + 1], t1 = sh[cq * 8 + c + 1];
                h00 = leakyf(h00 * s0 + t0);
                h01 = leakyf(h01 * s1 + t1);
                h10 = leakyf(h10 * s0 + t0);
                h11 = leakyf(h11 * s1 + t1);
            }
            *(float2*)&o0[c] = make_float2(h00, h01);
            *(float2*)&o1[c] = make_float2(h10, h11);
        }
    }
}

__device__ __forceinline__ void pool_store(const float* __restrict__ h,
                                           float* __restrict__ psc, int t) {
    const int ch = t & 31;
    const int hw = t >> 5;
    const int wave = t >> 6;
    float s = 0.f, m = -1e30f;
    for (int n = hw; n < ROI; n += 16) {
        float v = h[n * SR + ch];
        s += v;
        m = fmaxf(m, v);
    }
    s += __shfl_down(s, 32);
    m = fmaxf(m, __shfl_down(m, 32));
    if ((t & 63) < 32) {
        psc[wave * 32 + ch] = s;
        psc[256 + wave * 32 + ch] = m;
    }
}

__device__ __forceinline__ void pool_final(const float* __restrict__ psc,
                                           float* __restrict__ zg, int t) {
    if (t < 32) {
        float s = 0.f, m = -1e30f;
#pragma unroll
        for (int wv = 0; wv < 8; wv++) {
            s += psc[wv * 32 + t];
            m = fmaxf(m, psc[256 + wv * 32 + t]);
        }
        zg[t] = m;
        zg[CH + t] = s / (float)ROI;
    }
}

// ---------------------------------------------------------------------------
// K3: fused both GIN layers + both poolings. One 512-thr block per graph.
// ---------------------------------------------------------------------------
__global__ __launch_bounds__(512, 2) void k_gin(
    const float* __restrict__ y0, const int* __restrict__ row_ptr,
    const int* __restrict__ ebuf, const float* __restrict__ eps0p,
    const float* __restrict__ b1_0, const float* __restrict__ W2_0,
    const float* __restrict__ b2_0, const float* __restrict__ bn0_g,
    const float* __restrict__ bn0_b, const float* __restrict__ bn0_m,
    const float* __restrict__ bn0_v, const float* __restrict__ eps1p,
    const float* __restrict__ W1_1, const float* __restrict__ b1_1,
    const float* __restrict__ W2_1, const float* __restrict__ b2_1,
    const float* __restrict__ bn1_g, const float* __restrict__ bn1_b,
    const float* __restrict__ bn1_m, const float* __restrict__ bn1_v,
    float* __restrict__ z) {
    __shared__ float bufA[ROI * SR];
    __shared__ float bufB[ROI * SR];
    __shared__ float w[CH * CH];
    __shared__ float prm[8 * CH];
    __shared__ float psc[512];
    __shared__ float epss[2];

    const int t = threadIdx.x;
    const int g = blockIdx.x;

    if (t < CH) {
        prm[0 * CH + t] = b1_0[t];
        prm[1 * CH + t] = b2_0[t];
        float s0 = bn0_g[t] * rsqrtf(bn0_v[t] + BN_EPS);
        prm[2 * CH + t] = s0;
        prm[3 * CH + t] = bn0_b[t] - bn0_m[t] * s0;
        prm[4 * CH + t] = b1_1[t];
        prm[5 * CH + t] = b2_1[t];
        float s1 = bn1_g[t] * rsqrtf(bn1_v[t] + BN_EPS);
        prm[6 * CH + t] = s1;
        prm[7 * CH + t] = bn1_b[t] - bn1_m[t] * s1;
    }
    if (t == 0) {
        epss[0] = 1.0f + *eps0p;
        epss[1] = 1.0f + *eps1p;
    }

    const float* yg = y0 + (size_t)g * ROI * CH;
    for (int f = t; f < (ROI * CH) / 4; f += 512) {
        float4 v = ((const float4*)yg)[f];
        int row = f >> 3, c4 = (f & 7) << 2;
        float* p = &bufA[row * SR + c4];
        *(float2*)p = make_float2(v.x, v.y);
        *(float2*)(p + 2) = make_float2(v.z, v.w);
    }
    for (int i = t; i < (CH * CH) / 4; i += 512)
        ((float4*)w)[i] = ((const float4*)W2_0)[i];
    __syncthreads();

    const int* rp = row_ptr + g * RPS;

    gather_combine(bufA, bufB, rp, ebuf, epss[0], &prm[0 * CH], t);
    __syncthreads();

    gemm_inplace<true>(bufB, w, &prm[1 * CH], &prm[2 * CH], &prm[3 * CH], t);
    __syncthreads();

    pool_store(bufB, psc, t);
    for (int i = t; i < (CH * CH) / 4; i += 512)
        ((float4*)w)[i] = ((const float4*)W1_1)[i];
    __syncthreads();

    pool_final(psc, z + (size_t)g * 128, t);
    gemm_inplace<false>(bufB, w, nullptr, nullptr, nullptr, t);
    __syncthreads();

    gather_combine(bufB, bufA, rp, ebuf, epss[1], &prm[4 * CH], t);
    for (int i = t; i < (CH * CH) / 4; i += 512)
        ((float4*)w)[i] = ((const float4*)W2_1)[i];
    __syncthreads();

    gemm_inplace<true>(bufA, w, &prm[5 * CH], &prm[6 * CH], &prm[7 * CH], t);
    __syncthreads();

    pool_store(bufA, psc, t);
    __syncthreads();
    pool_final(psc, z + (size_t)g * 128 + 64, t);
}

// ---------------------------------------------------------------------------
// K4: head MLP  z[512,128] -> 256 -> 128 -> 1
// ---------------------------------------------------------------------------
__global__ __launch_bounds__(256) void k_head(
    const float* __restrict__ z, const float* __restrict__ W1,
    const float* __restrict__ b1, const float* __restrict__ g1,
    const float* __restrict__ be1, const float* __restrict__ m1,
    const float* __restrict__ v1, const float* __restrict__ W2,
    const float* __restrict__ b2, const float* __restrict__ g2,
    const float* __restrict__ be2, const float* __restrict__ m2,
    const float* __restrict__ v2, const float* __restrict__ W3,
    const float* __restrict__ b3, float* __restrict__ out) {
    __shared__ float zr[128], z1[256], z2[128];
    const int t = threadIdx.x;
    const int g = blockIdx.x;

    if (t < 32) ((float4*)zr)[t] = ((const float4*)(z + (size_t)g * 128))[t];
    __syncthreads();
    {
        float acc = b1[t];
#pragma unroll 8
        for (int k = 0; k < 128; k++) acc += zr[k] * W1[k * 256 + t];
        float s = g1[t] * rsqrtf(v1[t] + BN_EPS);
        acc = (acc - m1[t]) * s + be1[t];
        z1[t] = leakyf(acc);
    }
    __syncthreads();
    if (t < 128) {
        float acc = b2[t];
#pragma unroll 8
        for (int k = 0; k < 256; k++) acc += z1[k] * W2[k * 128 + t];
        float s = g2[t] * rsqrtf(v2[t] + BN_EPS);
        acc = (acc - m2[t]) * s + be2[t];
        z2[t] = leakyf(acc);
    }
    __syncthreads();
    if (t < 64) {
        float v = z2[t] * W3[t] + z2[t + 64] * W3[t + 64];
        for (int offd = 32; offd; offd >>= 1) v += __shfl_down(v, offd);
        if (t == 0) out[g] = v + b3[0];
    }
}

// ---------------------------------------------------------------------------
extern "C" void kernel_launch(void* const* d_in, const int* in_sizes, int n_in,
                              void* d_out, int out_size, void* d_ws, size_t ws_size,
                              hipStream_t stream) {
    const float* x      = (const float*)d_in[0];
    const int* eidx     = (const int*)d_in[1];
    const float* eps0   = (const float*)d_in[3];
    const float* W1_0   = (const float*)d_in[4];
    const float* b1_0   = (const float*)d_in[5];
    const float* W2_0   = (const float*)d_in[6];
    const float* b2_0   = (const float*)d_in[7];
    const float* bn0_g  = (const float*)d_in[8];
    const float* bn0_b  = (const float*)d_in[9];
    const float* bn0_m  = (const float*)d_in[10];
    const float* bn0_v  = (const float*)d_in[11];
    const float* eps1   = (const float*)d_in[12];
    const float* W1_1   = (const float*)d_in[13];
    const float* b1_1   = (const float*)d_in[14];
    const float* W2_1   = (const float*)d_in[15];
    const float* b2_1   = (const float*)d_in[16];
    const float* bn1_g  = (const float*)d_in[17];
    const float* bn1_b  = (const float*)d_in[18];
    const float* bn1_m  = (const float*)d_in[19];
    const float* bn1_v  = (const float*)d_in[20];
    const float* lin1_W = (const float*)d_in[21];
    const float* lin1_b = (const float*)d_in[22];
    const float* hbn1_g = (const float*)d_in[23];
    const float* hbn1_b = (const float*)d_in[24];
    const float* hbn1_m = (const float*)d_in[25];
    const float* hbn1_v = (const float*)d_in[26];
    const float* lin2_W = (const float*)d_in[27];
    const float* lin2_b = (const float*)d_in[28];
    const float* hbn2_g = (const float*)d_in[29];
    const float* hbn2_b = (const float*)d_in[30];
    const float* hbn2_m = (const float*)d_in[31];
    const float* hbn2_v = (const float*)d_in[32];
    const float* lin3_W = (const float*)d_in[33];
    const float* lin3_b = (const float*)d_in[34];

    const int E = in_sizes[1] / 2;
    const int* src = eidx;
    const int* dst = eidx + E;

    char* ws = (char*)d_ws;
    const size_t Y0_OFF  = 0;
    const size_t Z_OFF   = (size_t)NNODES * CH * 4;          // 17,563,648
    const size_t DEG_OFF = Z_OFF + (size_t)NG * 128 * 4;
    const size_t TKT_OFF = DEG_OFF + (size_t)NNODES * 4;     // ticket right after deg
    const size_t RP_OFF  = TKT_OFF + 64;
    const size_t EB_OFF  = RP_OFF + (size_t)(NG * RPS + 4) * 4;

    float* y0    = (float*)(ws + Y0_OFF);
    float* z     = (float*)(ws + Z_OFF);
    int* deg     = (int*)(ws + DEG_OFF);   // degree -> cursor
    int* ticket  = (int*)(ws + TKT_OFF);
    int* row_ptr = (int*)(ws + RP_OFF);
    int* ebuf    = (int*)(ws + EB_OFF);

    k_gemm1<<<NNODES / 256, 256, 0, stream>>>(x, W1_0, y0);

    hipMemsetAsync(deg, 0, (size_t)NNODES * sizeof(int) + 64, stream);
    k_deg<<<1024, 256, 0, stream>>>(dst, E, deg);
    k_scan_local<<<NG, 512, 0, stream>>>(deg, ticket, row_ptr);
    k_fill<<<1024, 256, 0, stream>>>(src, dst, E, deg, ebuf);

    k_gin<<<NG, 512, 0, stream>>>(y0, row_ptr, ebuf, eps0, b1_0, W2_0, b2_0,
                                  bn0_g, bn0_b, bn0_m, bn0_v, eps1, W1_1, b1_1,
                                  W2_1, b2_1, bn1_g, bn1_b, bn1_m, bn1_v, z);

    k_head<<<NG, 256, 0, stream>>>(z, lin1_W, lin1_b, hbn1_g, hbn1_b, hbn1_m,
                                   hbn1_v, lin2_W, lin2_b, hbn2_g, hbn2_b,
                                   hbn2_m, hbn2_v, lin3_W, lin3_b,
                                   (float*)d_out);
}